// Round 2
// baseline (469.956 us; speedup 1.0000x reference)
//
#include <hip/hip_runtime.h>

// Problem: T=2048, B=16, N=2048, binary fp32 spikes, duration=100.
// out[t,b,n] = 1 if any spike in window [t-duration+1, t], else 0.
// Streaming scan over time; time split into chunks of CHUNK=256 with a
// (duration-1)-step halo re-scan.
//
// This revision: force memory-level parallelism. Round-1 rocprof showed
// ~1 load in flight/wave (VGPR=28, 2.55 TB/s = waves*load/latency).
// Fix: explicit BATCH=8 register array of float4 loads (compiler must
// issue 8 independent 1-KiB wave-loads before the compute loop), batched
// halo too. 8 KiB/wave in flight -> HBM-saturated even at 4 waves/CU.

#define T_TOTAL 2048
#define M_COLS  (16 * 2048)   // B*N, contiguous fastest axis
#define CHUNK   256           // time steps per block (halo overhead 99/256)
#define VEC     4             // columns per thread (float4, 16 B/lane)
#define BATCH   8             // loads in flight per wave

typedef float v4f __attribute__((ext_vector_type(4)));

__global__ __launch_bounds__(256) void psp_scan_kernel(
    const float* __restrict__ x,
    const int*  __restrict__ dur_p,
    float* __restrict__ out)
{
    const int quad = blockIdx.x * blockDim.x + threadIdx.x;  // 0 .. M_COLS/4-1
    const int col  = quad * VEC;
    const int t0   = blockIdx.y * CHUNK;
    const int duration = dur_p[0];                            // uniform scalar load

    // sentinel: guarantees (t - last) >= duration for all t >= t0 until a spike
    int last0 = t0 - duration;
    int last1 = last0, last2 = last0, last3 = last0;

    int tstart = t0 - duration + 1;
    if (tstart < 0) tstart = 0;

    const v4f* __restrict__ xc = (const v4f*)(x + col);
    v4f* __restrict__ oc       = (v4f*)(out + col);
    const int stride = M_COLS / VEC;   // row stride in float4 units

    // ---- Halo: recover "last spike time" entering this chunk (batched) ----
    int t = tstart;
    for (; t + BATCH <= t0; t += BATCH) {
        v4f v[BATCH];
        #pragma unroll
        for (int i = 0; i < BATCH; ++i) v[i] = xc[(t + i) * stride];
        #pragma unroll
        for (int i = 0; i < BATCH; ++i) {
            const int tt = t + i;
            if (v[i].x != 0.0f) last0 = tt;
            if (v[i].y != 0.0f) last1 = tt;
            if (v[i].z != 0.0f) last2 = tt;
            if (v[i].w != 0.0f) last3 = tt;
        }
    }
    for (; t < t0; ++t) {                      // <= BATCH-1 remainder steps
        v4f v = xc[t * stride];
        if (v.x != 0.0f) last0 = t;
        if (v.y != 0.0f) last1 = t;
        if (v.z != 0.0f) last2 = t;
        if (v.w != 0.0f) last3 = t;
    }

    // ---- Main chunk: scan + emit, BATCH loads in flight ----
    for (int tb = t0; tb < t0 + CHUNK; tb += BATCH) {
        v4f v[BATCH];
        #pragma unroll
        for (int i = 0; i < BATCH; ++i) v[i] = xc[(tb + i) * stride];
        #pragma unroll
        for (int i = 0; i < BATCH; ++i) {
            const int tt = tb + i;
            if (v[i].x != 0.0f) last0 = tt;
            if (v[i].y != 0.0f) last1 = tt;
            if (v[i].z != 0.0f) last2 = tt;
            if (v[i].w != 0.0f) last3 = tt;
            v4f o;
            o.x = (tt - last0 < duration) ? 1.0f : 0.0f;
            o.y = (tt - last1 < duration) ? 1.0f : 0.0f;
            o.z = (tt - last2 < duration) ? 1.0f : 0.0f;
            o.w = (tt - last3 < duration) ? 1.0f : 0.0f;
            __builtin_nontemporal_store(o, &oc[tt * stride]);
        }
    }
}

extern "C" void kernel_launch(void* const* d_in, const int* in_sizes, int n_in,
                              void* d_out, int out_size, void* d_ws, size_t ws_size,
                              hipStream_t stream) {
    const float* x     = (const float*)d_in[0];
    const int*   dur_p = (const int*)d_in[1];
    float*       out   = (float*)d_out;

    dim3 grid(M_COLS / VEC / 256, T_TOTAL / CHUNK);   // (32, 8) = 256 blocks
    dim3 block(256);
    psp_scan_kernel<<<grid, block, 0, stream>>>(x, dur_p, out);
}

// Round 3
// 465.756 us; speedup vs baseline: 1.0090x; 1.0090x over previous
//
#include <hip/hip_runtime.h>

// Problem: T=2048, B=16, N=2048, binary fp32 spikes, duration=100.
// out[t,b,n] = 1 if any spike in window [t-duration+1, t], else 0.
//
// R2 post-mortem: VGPR=32 proved the compiler re-fused the batch-load loop
// into the use loop (1 load in flight/wave; 2.45 TB/s = Little's law at
// ~375ns). This revision forces MLP:
//   * __launch_bounds__(256,1): kill the pressure-driven scheduler target
//   * ping-pong pipeline (va/vb, static indexing): consumer waits on
//     counted vmcnt(8), never vmcnt(0)
//   * sched_barrier(0) after each load cluster: scheduler cannot re-sink
// VEC=2 -> 512 blocks = 8 waves/CU for TLP on top of the 4KB/wave ILP.

#define T_TOTAL 2048
#define M_COLS  (16 * 2048)   // B*N, contiguous fastest axis
#define CHUNK   256           // time steps per block
#define VEC     2             // columns per thread (float2)
#define BATCH   8             // loads in flight per wave

typedef float v2f __attribute__((ext_vector_type(2)));

__device__ __forceinline__ void loadb(v2f (&dst)[BATCH], const v2f* __restrict__ xc,
                                      int tb, int stride) {
    #pragma unroll
    for (int i = 0; i < BATCH; ++i) dst[i] = xc[(tb + i) * stride];
}

__device__ __forceinline__ void procb(const v2f (&v)[BATCH], v2f* __restrict__ oc,
                                      int tb, int stride, int t0, int duration,
                                      int& last0, int& last1) {
    #pragma unroll
    for (int i = 0; i < BATCH; ++i) {
        const int tt = tb + i;
        if (v[i].x != 0.0f) last0 = tt;
        if (v[i].y != 0.0f) last1 = tt;
        if (tt >= t0) {                         // uniform: batches never straddle t0
            v2f o;
            o.x = (tt - last0 < duration) ? 1.0f : 0.0f;
            o.y = (tt - last1 < duration) ? 1.0f : 0.0f;
            __builtin_nontemporal_store(o, &oc[tt * stride]);
        }
    }
}

__global__ __launch_bounds__(256, 1) void psp_scan_kernel(
    const float* __restrict__ x,
    const int*  __restrict__ dur_p,
    float* __restrict__ out)
{
    const int pair = blockIdx.x * blockDim.x + threadIdx.x;  // 0 .. M_COLS/2-1
    const int col  = pair * VEC;
    const int t0   = blockIdx.y * CHUNK;
    const int duration = dur_p[0];                            // uniform scalar

    // Halo rounded up to whole batches so batches stay aligned to t0.
    int hal = (duration - 1 + (BATCH - 1)) & ~(BATCH - 1);    // 104 for dur=100
    if (hal > t0) hal = t0;                                   // t0 is a multiple of 8
    const int tstart = t0 - hal;
    const int NB = (hal + CHUNK) / BATCH;                     // whole batches

    // sentinel: guarantees (t - last) >= duration until first spike seen
    int last0 = tstart - duration;
    int last1 = last0;

    const v2f* __restrict__ xc = (const v2f*)(x + col);
    v2f* __restrict__ oc       = (v2f*)(out + col);
    const int stride = M_COLS / VEC;

    v2f va[BATCH], vb[BATCH];

    int t = tstart;
    loadb(va, xc, t, stride);

    int b = 0;
    while (b + 2 <= NB) {
        loadb(vb, xc, t + BATCH, stride);
        __builtin_amdgcn_sched_barrier(0);
        procb(va, oc, t, stride, t0, duration, last0, last1);

        if (b + 2 < NB) loadb(va, xc, t + 2 * BATCH, stride);
        __builtin_amdgcn_sched_barrier(0);
        procb(vb, oc, t + BATCH, stride, t0, duration, last0, last1);

        t += 2 * BATCH;
        b += 2;
    }
    if (b < NB) {   // odd batch count tail (halo case: NB=45)
        procb(va, oc, t, stride, t0, duration, last0, last1);
    }
}

extern "C" void kernel_launch(void* const* d_in, const int* in_sizes, int n_in,
                              void* d_out, int out_size, void* d_ws, size_t ws_size,
                              hipStream_t stream) {
    const float* x     = (const float*)d_in[0];
    const int*   dur_p = (const int*)d_in[1];
    float*       out   = (float*)d_out;

    dim3 grid(M_COLS / VEC / 256, T_TOTAL / CHUNK);   // (64, 8) = 512 blocks
    dim3 block(256);
    psp_scan_kernel<<<grid, block, 0, stream>>>(x, dur_p, out);
}